// Round 10
// baseline (712.775 us; speedup 1.0000x reference)
//
#include <hip/hip_runtime.h>
#include <hip/hip_bf16.h>

#define N_EMBD 1024
#define N_HEAD 16
#define HEAD_DIM 64
#define BATCH 8
#define SEQ_T 1024
#define SEQ_I 257

typedef __attribute__((ext_vector_type(8))) short short8_t;
typedef __attribute__((ext_vector_type(4))) float f32x4;

union U8 { uint4 u; short8_t s; };

// f32 -> bf16 RNE
static __device__ __forceinline__ unsigned short f2b(float f)
{
    unsigned int u = __float_as_uint(f);
    u = (u + 0x7fffu + ((u >> 16) & 1u)) >> 16;
    return (unsigned short)u;
}

__device__ __forceinline__ float gelu_tanh(float u)
{
    float z = 0.7978845608028654f * (u + 0.044715f * u * u * u);
    z = fmaxf(z, -15.0f);
    const float e = __expf(-2.0f * z);
    const float t = (1.0f - e) / (1.0f + e);
    return 0.5f * u * (1.0f + t);
}

// ---------------------------------------------------------------------------
// Weight transpose+cast: W[K,N] f32 -> WT[N,K] bf16
// ---------------------------------------------------------------------------
__global__ __launch_bounds__(256)
void wcast_t(const float* __restrict__ W, short* __restrict__ WT, int K, int N)
{
    __shared__ float t[32][33];
    const int n0 = blockIdx.x * 32, k0 = blockIdx.y * 32;
    const int c = threadIdx.x & 31, r4 = (threadIdx.x >> 5) * 4;
    #pragma unroll
    for (int i = 0; i < 4; ++i)
        t[r4 + i][c] = W[(size_t)(k0 + r4 + i) * N + n0 + c];
    __syncthreads();
    #pragma unroll
    for (int i = 0; i < 4; ++i)
        WT[(size_t)(n0 + r4 + i) * K + k0 + c] = (short)f2b(t[c][r4 + i]);
}

// elementwise f32 -> bf16 (enc), 4 elems/thread
__global__ __launch_bounds__(256)
void cast_bf16(const float* __restrict__ in, short* __restrict__ out)
{
    const int i = blockIdx.x * 256 + threadIdx.x;
    const float4 v = ((const float4*)in)[i];
    unsigned int w0 = (unsigned int)f2b(v.x) | ((unsigned int)f2b(v.y) << 16);
    unsigned int w1 = (unsigned int)f2b(v.z) | ((unsigned int)f2b(v.w) << 16);
    ((uint2*)out)[i] = make_uint2(w0, w1);
}

// ---------------------------------------------------------------------------
// LayerNorm: f32 in -> bf16 out. one block per row of 1024.
// ---------------------------------------------------------------------------
__global__ __launch_bounds__(256)
void ln_bf16(const float* __restrict__ in, const float* __restrict__ gamma,
             const float* __restrict__ beta, short* __restrict__ out)
{
    const int row = blockIdx.x;
    const int tid = threadIdx.x;
    const float4 v = *(const float4*)(in + (size_t)row * N_EMBD + tid * 4);
    float s  = v.x + v.y + v.z + v.w;
    float ss = v.x*v.x + v.y*v.y + v.z*v.z + v.w*v.w;
    #pragma unroll
    for (int off = 32; off >= 1; off >>= 1) {
        s  += __shfl_down(s,  off);
        ss += __shfl_down(ss, off);
    }
    __shared__ float rs[4], rss[4];
    const int wid = tid >> 6, lane = tid & 63;
    if (lane == 0) { rs[wid] = s; rss[wid] = ss; }
    __syncthreads();
    s  = rs[0] + rs[1] + rs[2] + rs[3];
    ss = rss[0] + rss[1] + rss[2] + rss[3];
    const float mean = s * (1.0f / N_EMBD);
    const float var  = ss * (1.0f / N_EMBD) - mean * mean;
    const float rstd = rsqrtf(var + 1e-5f);
    const float4 g = *(const float4*)(gamma + tid * 4);
    const float4 b = *(const float4*)(beta  + tid * 4);
    float o0 = (v.x - mean) * rstd * g.x + b.x;
    float o1 = (v.y - mean) * rstd * g.y + b.y;
    float o2 = (v.z - mean) * rstd * g.z + b.z;
    float o3 = (v.w - mean) * rstd * g.w + b.w;
    unsigned int w0 = (unsigned int)f2b(o0) | ((unsigned int)f2b(o1) << 16);
    unsigned int w1 = (unsigned int)f2b(o2) | ((unsigned int)f2b(o3) << 16);
    ((uint2*)(out + (size_t)row * N_EMBD))[tid] = make_uint2(w0, w1);
}

// ---------------------------------------------------------------------------
// bf16 MFMA GEMM v3: 128x128 tile, BK=32, TRIPLE-buffered LDS, prefetch
// distance 2 K-tiles, raw s_barrier + counted vmcnt(4) (no vmcnt(0) drain
// in the main loop). XCD-chunked swizzle with m-fastest-within-chunk (mpc
// m-tiles per chunk) so the chunk working set (mpc A-panels + W band) fits L2.
// LDS involution: 16B slot s of row r holds global k-group s ^ (r&3).
// EPI: 0 = bias -> bf16 out; 1 = bias + res(f32) -> f32 out; 2 = bias+gelu -> bf16
// ---------------------------------------------------------------------------
template<int EPI>
__global__ __launch_bounds__(256, 3)
void gemm_mfma(const short* __restrict__ A, const short* __restrict__ WT,
               const float* __restrict__ bias, const float* __restrict__ res,
               void* __restrict__ outv, int M, int N, int K, int lda,
               int gnx, int mpc)
{
    __shared__ short As[3][128 * 32];
    __shared__ short Bs[3][128 * 32];
    const int tid = threadIdx.x;

    // XCD-chunked bijective swizzle; within chunk m varies fastest (mpc>1)
    const int nwg = gridDim.x;
    const int cs  = nwg >> 3;
    const int xcd = blockIdx.x & 7;
    const int loc = blockIdx.x >> 3;
    int bmi, bni;
    if (mpc > 1) { bmi = xcd * mpc + (loc % mpc); bni = loc / mpc; }
    else { const int lin = xcd * cs + loc; bmi = lin / gnx; bni = lin % gnx; }
    const int bm = bmi * 128;
    const int bn = bni * 128;

    const int lane = tid & 63;
    const int wid  = tid >> 6;
    const int wr   = (wid >> 1) * 64;
    const int wc   = (wid & 1) * 64;
    const int fr   = lane & 15;
    const int kg   = lane >> 4;          // k-group 0..3 (8 shorts each)

    // staging: chunk c = p*256+tid covers row r=c>>2, LDS slot c&3,
    // global k-group (c&3)^(r&3). dst base excludes lane (HW adds lane*16).
    const int r0_ = tid >> 2;            // p=0 rows 0..63
    const int r1_ = (256 + tid) >> 2;    // p=1 rows 64..127
    const int g0_ = (tid & 3) ^ (r0_ & 3);
    const int g1_ = (tid & 3) ^ (r1_ & 3);
    const int dst0 = (tid & ~63) * 16;
    const int dst1 = 4096 + (tid & ~63) * 16;

    #define STAGE(buf, k0)                                                      \
        {                                                                       \
            const int rowA0 = min(bm + r0_, M - 1);                             \
            const int rowA1 = min(bm + r1_, M - 1);                             \
            __builtin_amdgcn_global_load_lds(                                   \
                (const __attribute__((address_space(1))) void*)                 \
                    (A + (size_t)rowA0 * lda + (k0) + g0_ * 8),                 \
                (__attribute__((address_space(3))) void*)                       \
                    ((char*)As[buf] + dst0), 16, 0, 0);                         \
            __builtin_amdgcn_global_load_lds(                                   \
                (const __attribute__((address_space(1))) void*)                 \
                    (A + (size_t)rowA1 * lda + (k0) + g1_ * 8),                 \
                (__attribute__((address_space(3))) void*)                       \
                    ((char*)As[buf] + dst1), 16, 0, 0);                         \
            __builtin_amdgcn_global_load_lds(                                   \
                (const __attribute__((address_space(1))) void*)                 \
                    (WT + (size_t)(bn + r0_) * K + (k0) + g0_ * 8),             \
                (__attribute__((address_space(3))) void*)                       \
                    ((char*)Bs[buf] + dst0), 16, 0, 0);                         \
            __builtin_amdgcn_global_load_lds(                                   \
                (const __attribute__((address_space(1))) void*)                 \
                    (WT + (size_t)(bn + r1_) * K + (k0) + g1_ * 8),             \
                (__attribute__((address_space(3))) void*)                       \
                    ((char*)Bs[buf] + dst1), 16, 0, 0);                         \
        }

    f32x4 acc[4][4];
    #pragma unroll
    for (int i = 0; i < 4; ++i)
        #pragma unroll
        for (int j = 0; j < 4; ++j)
            acc[i][j] = (f32x4){0.f, 0.f, 0.f, 0.f};

    // prologue: stage tiles 0,1; wait tile 0 (keep tile 1 in flight)
    STAGE(0, 0);
    STAGE(1, 32);
    asm volatile("s_waitcnt vmcnt(4)" ::: "memory");
    __builtin_amdgcn_s_barrier();
    __builtin_amdgcn_sched_barrier(0);

    const int nkt = K >> 5;
    int bc = 0, bs = 2;
    for (int t = 0; t < nkt; ++t) {
        if (t + 2 < nkt) STAGE(bs, (t + 2) << 5);

        const short* AsC = As[bc];
        const short* BsC = Bs[bc];
        short8_t af[4], bf[4];
        #pragma unroll
        for (int f = 0; f < 4; ++f) {
            const int ra = wr + f * 16 + fr;
            af[f] = *(const short8_t*)(AsC + ra * 32 + ((kg ^ (ra & 3)) * 8));
            const int rb = wc + f * 16 + fr;
            bf[f] = *(const short8_t*)(BsC + rb * 32 + ((kg ^ (rb & 3)) * 8));
        }
        #pragma unroll
        for (int i = 0; i < 4; ++i)
            #pragma unroll
            for (int j = 0; j < 4; ++j)
                acc[i][j] = __builtin_amdgcn_mfma_f32_16x16x32_bf16(af[i], bf[j], acc[i][j], 0, 0, 0);

        // wait: next tile's 4 loads landed (this tile's t+2 prefetch stays in flight)
        asm volatile("s_waitcnt vmcnt(4)" ::: "memory");
        __builtin_amdgcn_s_barrier();
        __builtin_amdgcn_sched_barrier(0);
        bc = (bc == 2) ? 0 : bc + 1;
        bs = (bs == 2) ? 0 : bs + 1;
    }
    #undef STAGE

    // epilogue: C/D frag: n = lane&15, m = (lane>>4)*4 + r
    #pragma unroll
    for (int i = 0; i < 4; ++i) {
        #pragma unroll
        for (int r = 0; r < 4; ++r) {
            const int m = bm + wr + i * 16 + kg * 4 + r;
            if (m >= M) continue;
            #pragma unroll
            for (int j = 0; j < 4; ++j) {
                const int n = bn + wc + j * 16 + fr;
                float v = acc[i][j][r] + bias[n];
                if (EPI == 1) v += res[(size_t)m * N + n];
                if (EPI == 2) v = gelu_tanh(v);
                if (EPI == 1) ((float*)outv)[(size_t)m * N + n] = v;
                else          ((short*)outv)[(size_t)m * N + n] = (short)f2b(v);
            }
        }
    }
}

// ---------------------------------------------------------------------------
// MFMA flash attention (unchanged from round 7).
// ---------------------------------------------------------------------------
template<bool CAUSAL>
__global__ __launch_bounds__(256, 2)
void attn_mfma(const short* __restrict__ Qm, const short* __restrict__ Km,
               const short* __restrict__ Vm, short* __restrict__ out,
               int qStride, int kStride, int kRows)
{
    __shared__ short Ks[32 * 64];            // [key][64 d], slot-swizzled
    __shared__ unsigned int VtU[36 * 32];    // V^T [64 d][36 shorts] as uints
    __shared__ unsigned int PA[4][320];      // per wave: P[16 q][40 shorts]

    const int tid  = threadIdx.x;
    const int lane = tid & 63;
    const int wid  = tid >> 6;
    const int bid  = blockIdx.x;
    const int qt   = CAUSAL ? (15 - (bid >> 7)) : (bid >> 7);
    const int bh   = bid & 127;
    const int b    = bh >> 4, h = bh & 15;
    const int qb   = qt * 64;
    const int fr   = lane & 15;
    const int g    = lane >> 4;

    const int qrow = qb + wid * 16 + fr;
    const short* qptr = Qm + (size_t)(b * SEQ_T + qrow) * qStride + h * HEAD_DIM + g * 8;
    U8 qf0, qf1;
    qf0.u = *(const uint4*)(qptr);
    qf1.u = *(const uint4*)(qptr + 32);

    f32x4 accO[4];
    #pragma unroll
    for (int i = 0; i < 4; ++i) accO[i] = (f32x4){0.f, 0.f, 0.f, 0.f};
    float mrun = -1e30f, lrun = 0.f;

    const int ntiles = CAUSAL ? (2 * qt + 2) : ((kRows + 31) >> 5);
    const size_t kbase = (size_t)b * kRows;

    for (int it = 0; it < ntiles; ++it) {
        const int kb = it * 32;
        __syncthreads();

        {
            const int krow  = min(kb + (tid >> 3), kRows - 1);
            const int gslot = (tid & 7) ^ ((tid >> 3) & 7);
            __builtin_amdgcn_global_load_lds(
                (const __attribute__((address_space(1))) void*)
                    (Km + (kbase + krow) * (size_t)kStride + h * HEAD_DIM + gslot * 8),
                (__attribute__((address_space(3))) void*)((char*)Ks + tid * 16), 16, 0, 0);
        }
        #pragma unroll
        for (int v = 0; v < 2; ++v) {
            const int idx = v * 256 + tid;
            const int d2 = idx & 31, kp = idx >> 5;
            const int kr0 = min(kb + 2 * kp,     kRows - 1);
            const int kr1 = min(kb + 2 * kp + 1, kRows - 1);
            const unsigned int u0 = *(const unsigned int*)
                (Vm + (kbase + kr0) * (size_t)kStride + h * HEAD_DIM + 2 * d2);
            const unsigned int u1 = *(const unsigned int*)
                (Vm + (kbase + kr1) * (size_t)kStride + h * HEAD_DIM + 2 * d2);
            VtU[36 * d2 + kp]      = (u0 & 0xffffu) | (u1 << 16);
            VtU[36 * d2 + 18 + kp] = (u0 >> 16)    | (u1 & 0xffff0000u);
        }
        __syncthreads();

        f32x4 s0 = (f32x4){0.f,0.f,0.f,0.f}, s1 = (f32x4){0.f,0.f,0.f,0.f};
        {
            const uint4* K4 = (const uint4*)Ks;
            U8 ka;
            ka.u = K4[8 * fr        + ((g)     ^ (fr & 7))];
            s0 = __builtin_amdgcn_mfma_f32_16x16x32_bf16(ka.s, qf0.s, s0, 0, 0, 0);
            ka.u = K4[8 * fr        + ((4 + g) ^ (fr & 7))];
            s0 = __builtin_amdgcn_mfma_f32_16x16x32_bf16(ka.s, qf1.s, s0, 0, 0, 0);
            ka.u = K4[8 * (16 + fr) + ((g)     ^ (fr & 7))];
            s1 = __builtin_amdgcn_mfma_f32_16x16x32_bf16(ka.s, qf0.s, s1, 0, 0, 0);
            ka.u = K4[8 * (16 + fr) + ((4 + g) ^ (fr & 7))];
            s1 = __builtin_amdgcn_mfma_f32_16x16x32_bf16(ka.s, qf1.s, s1, 0, 0, 0);
        }

        float sv[8];
        #pragma unroll
        for (int r = 0; r < 4; ++r) {
            sv[r]     = s0[r] * 0.125f;
            sv[4 + r] = s1[r] * 0.125f;
            const int k0 = kb + 4 * g + r;
            const int k1 = k0 + 16;
            if (CAUSAL ? (k0 > qrow) : (k0 >= kRows)) sv[r]     = -1e30f;
            if (CAUSAL ? (k1 > qrow) : (k1 >= kRows)) sv[4 + r] = -1e30f;
        }
        float tm = sv[0];
        #pragma unroll
        for (int j = 1; j < 8; ++j) tm = fmaxf(tm, sv[j]);
        tm = fmaxf(tm, __shfl_xor(tm, 16));
        tm = fmaxf(tm, __shfl_xor(tm, 32));
        const float newm = fmaxf(mrun, tm);
        const float fs = __expf(mrun - newm);
        mrun = newm;
        float p[8], ps = 0.f;
        #pragma unroll
        for (int j = 0; j < 8; ++j) { p[j] = __expf(sv[j] - newm); ps += p[j]; }
        ps += __shfl_xor(ps, 16);
        ps += __shfl_xor(ps, 32);
        lrun = lrun * fs + ps;

        float frr[4];
        #pragma unroll
        for (int r = 0; r < 4; ++r) frr[r] = __shfl(fs, 4 * g + r);
        #pragma unroll
        for (int db = 0; db < 4; ++db)
            #pragma unroll
            for (int r = 0; r < 4; ++r) accO[db][r] *= frr[r];

        {
            uint2* paw = (uint2*)PA[wid];
            paw[10 * fr + g] = make_uint2(
                (unsigned int)f2b(p[0]) | ((unsigned int)f2b(p[1]) << 16),
                (unsigned int)f2b(p[2]) | ((unsigned int)f2b(p[3]) << 16));
            paw[10 * fr + 4 + g] = make_uint2(
                (unsigned int)f2b(p[4]) | ((unsigned int)f2b(p[5]) << 16),
                (unsigned int)f2b(p[6]) | ((unsigned int)f2b(p[7]) << 16));
        }
        U8 pf;
        pf.u = ((const uint4*)PA[wid])[5 * fr + g];

        #pragma unroll
        for (int db = 0; db < 4; ++db) {
            const int d = db * 16 + fr;
            const uint2 v0 = ((const uint2*)VtU)[9 * d + 2 * g];
            const uint2 v1 = ((const uint2*)VtU)[9 * d + 2 * g + 1];
            U8 vf; vf.u = make_uint4(v0.x, v0.y, v1.x, v1.y);
            accO[db] = __builtin_amdgcn_mfma_f32_16x16x32_bf16(pf.s, vf.s, accO[db], 0, 0, 0);
        }
    }

    float lr[4];
    #pragma unroll
    for (int r = 0; r < 4; ++r) lr[r] = 1.0f / __shfl(lrun, 4 * g + r);
    #pragma unroll
    for (int db = 0; db < 4; ++db) {
        #pragma unroll
        for (int r = 0; r < 4; ++r) {
            const int row = qb + wid * 16 + 4 * g + r;
            const int col = h * HEAD_DIM + db * 16 + fr;
            out[(size_t)(b * SEQ_T + row) * N_EMBD + col] = (short)f2b(accO[db][r] * lr[r]);
        }
    }
}

// ---------------------------------------------------------------------------
// launch
// ---------------------------------------------------------------------------
extern "C" void kernel_launch(void* const* d_in, const int* in_sizes, int n_in,
                              void* d_out, int out_size, void* d_ws, size_t ws_size,
                              hipStream_t stream)
{
    const float* x     = (const float*)d_in[0];
    const float* enc   = (const float*)d_in[1];
    const float* ln1_g = (const float*)d_in[2];
    const float* ln1_b = (const float*)d_in[3];
    const float* ln2_g = (const float*)d_in[4];
    const float* ln2_b = (const float*)d_in[5];
    const float* ln3_g = (const float*)d_in[6];
    const float* ln3_b = (const float*)d_in[7];
    const float* w_qkv = (const float*)d_in[8];
    const float* b_qkv = (const float*)d_in[9];
    const float* w_ao  = (const float*)d_in[10];
    const float* b_ao  = (const float*)d_in[11];
    const float* w_q   = (const float*)d_in[12];
    const float* b_q   = (const float*)d_in[13];
    const float* w_kv  = (const float*)d_in[14];
    const float* b_kv  = (const float*)d_in[15];
    const float* w_co  = (const float*)d_in[16];
    const float* b_co  = (const float*)d_in[17];
    const float* w_fc  = (const float*)d_in[18];
    const float* b_fc  = (const float*)d_in[19];
    const float* w_mo  = (const float*)d_in[20];
    const float* b_mo  = (const float*)d_in[21];
    float* outp = (float*)d_out;

    // workspace layout
    short* wt_qkv = (short*)d_ws;
    short* wt_ao  = wt_qkv + 3145728;
    short* wt_q   = wt_ao  + 1048576;
    short* wt_kv  = wt_q   + 1048576;
    short* wt_co  = wt_kv  + 2097152;
    short* wt_fc  = wt_co  + 1048576;
    short* wt_mo  = wt_fc  + 4194304;
    short* enc_b  = wt_mo  + 4194304;                 // 2,105,344 bf16
    short* y_b    = enc_b  + 2105344;                 // 8,388,608 bf16
    short* qkv_b  = y_b    + 8388608;                 // region shared with h_b
    short* h_b    = qkv_b;
    short* attn_b = qkv_b  + 33554432;
    short* q_b    = attn_b + 8388608;
    float* x1     = (float*)(q_b + 8388608);
    float* x2     = x1 + 8388608;
    short* kv_b   = (short*)(x2 + 8388608);

    const int ROWS  = BATCH * SEQ_T;   // 8192
    const int EROWS = BATCH * SEQ_I;   // 2056

    // weight transpose+cast (bf16 W^T)
    wcast_t<<<dim3(3072/32, 1024/32), 256, 0, stream>>>(w_qkv, wt_qkv, 1024, 3072);
    wcast_t<<<dim3(1024/32, 1024/32), 256, 0, stream>>>(w_ao,  wt_ao,  1024, 1024);
    wcast_t<<<dim3(1024/32, 1024/32), 256, 0, stream>>>(w_q,   wt_q,   1024, 1024);
    wcast_t<<<dim3(2048/32, 1024/32), 256, 0, stream>>>(w_kv,  wt_kv,  1024, 2048);
    wcast_t<<<dim3(1024/32, 1024/32), 256, 0, stream>>>(w_co,  wt_co,  1024, 1024);
    wcast_t<<<dim3(4096/32, 1024/32), 256, 0, stream>>>(w_fc,  wt_fc,  1024, 4096);
    wcast_t<<<dim3(1024/32, 4096/32), 256, 0, stream>>>(w_mo,  wt_mo,  4096, 1024);
    cast_bf16<<<2056, 256, 0, stream>>>(enc, enc_b);

    // 1. y1 = LN(x) -> bf16
    ln_bf16<<<ROWS, 256, 0, stream>>>(x, ln1_g, ln1_b, y_b);
    // 2. qkv = y1 @ w_qkv + b_qkv -> bf16 [8192,3072]  grid 1536, gnx 24, mpc 8
    gemm_mfma<0><<<1536, 256, 0, stream>>>(
        y_b, wt_qkv, b_qkv, nullptr, qkv_b, ROWS, 3072, 1024, 1024, 24, 8);
    // 3. self attention (causal, MFMA) -> bf16 [8192,1024]
    attn_mfma<true><<<2048, 256, 0, stream>>>(
        qkv_b, qkv_b + 1024, qkv_b + 2048, attn_b, 3072, 3072, SEQ_T);
    // 4. x1 = x + attn @ w_ao + b_ao -> f32  grid 512, gnx 8, mpc 8
    gemm_mfma<1><<<512, 256, 0, stream>>>(
        attn_b, wt_ao, b_ao, x, x1, ROWS, 1024, 1024, 1024, 8, 8);
    // 5. y2 = LN(x1) -> bf16
    ln_bf16<<<ROWS, 256, 0, stream>>>(x1, ln2_g, ln2_b, y_b);
    // 6. q = y2 @ w_q + b_q -> bf16  grid 512
    gemm_mfma<0><<<512, 256, 0, stream>>>(
        y_b, wt_q, b_q, nullptr, q_b, ROWS, 1024, 1024, 1024, 8, 8);
    // 7. kv = enc @ w_kv + b_kv -> bf16 [2056,2048]  grid 272, gnx 16, mpc 1
    gemm_mfma<0><<<272, 256, 0, stream>>>(
        enc_b, wt_kv, b_kv, nullptr, kv_b, EROWS, 2048, 1024, 1024, 16, 1);
    // 8. cross attention (MFMA) -> bf16 (reuse attn_b)
    attn_mfma<false><<<2048, 256, 0, stream>>>(
        q_b, kv_b, kv_b + 1024, attn_b, 1024, 2048, SEQ_I);
    // 9. x2 = x1 + cross @ w_co + b_co -> f32  grid 512
    gemm_mfma<1><<<512, 256, 0, stream>>>(
        attn_b, wt_co, b_co, x1, x2, ROWS, 1024, 1024, 1024, 8, 8);
    // 10. y3 = LN(x2) -> bf16
    ln_bf16<<<ROWS, 256, 0, stream>>>(x2, ln3_g, ln3_b, y_b);
    // 11. h = gelu(y3 @ w_fc + b_fc) -> bf16 [8192,4096]  grid 2048, gnx 32, mpc 8
    gemm_mfma<2><<<2048, 256, 0, stream>>>(
        y_b, wt_fc, b_fc, nullptr, h_b, ROWS, 4096, 1024, 1024, 32, 8);
    // 12. out = x2 + h @ w_mo + b_mo -> f32  grid 512, K=4096
    gemm_mfma<1><<<512, 256, 0, stream>>>(
        h_b, wt_mo, b_mo, x2, outp, ROWS, 1024, 4096, 4096, 8, 8);
}